// Round 6
// baseline (66.171 us; speedup 1.0000x reference)
//
#include <hip/hip_runtime.h>

// Problem shape (fixed by reference setup_inputs):
//   x: [B=32, C=256, H=64, W=64] fp32, conv_w: [1,1,3] fp32
//   out: [B, 3, H, W] fp32
#define B    32
#define C    256
#define HW   4096          // 64*64
#define BC   (B * C)       // 8192
#define NBLK 1024          // 32 blocks per batch

// ---------------------------------------------------------------------------
// Single kernel, atomic handshake (no cooperative launch):
//  Phase 1: block g computes means of 8 slices of batch b=g>>5 (wave w does
//           slices 8g+2w, 8g+2w+1; 16 float4 loads in flight per wave).
//           Means published with atomicExch (device-coherent point, no dirty
//           L2 residue). Per-batch counter incremented once per block.
//  Phase 2: the 32nd finisher of a batch reads the 256 means back via
//           atomicAdd(+0) (coherent), conv1d(k=3,SAME) + wave-butterfly
//           top-3 (sigmoid skipped: monotonic; lax.top_k smaller-index
//           tie-break via key=(mono_u32(y)<<8)|(255-c)), packs 3 channel ids
//           + ready bit into one u32, atomicExch into flag[b].
//  Phase 3: every block spins (thread 0, s_sleep backoff) on flag[b] — safe:
//           each spinner IS a producer of batch b, so the 32-block group is
//           self-sufficient; all 1024 blocks are co-resident anyway
//           (__launch_bounds__(256,4) -> >=4 blocks/CU). Then copies its
//           96 float4 of output (x is L3-resident after phase 1).
// Control words (ctr[32], flag[32]) are zeroed by a hipMemsetAsync node each
// call (d_ws is poisoned 0xAA once and never re-poisoned between replays).
// ---------------------------------------------------------------------------
__global__ __launch_bounds__(256, 4) void eca_one_kernel(
    const float* __restrict__ x, const float* __restrict__ w,
    float* means, unsigned int* ctr, unsigned int* flag,
    float* __restrict__ out) {
    const int g    = blockIdx.x;
    const int tid  = threadIdx.x;
    const int lane = tid & 63;
    const int wave = tid >> 6;
    const int b    = g >> 5;

    const float4* x4 = reinterpret_cast<const float4*>(x);

    // ---------------- Phase 1: means of 8 slices ----------------
#pragma unroll
    for (int s = 0; s < 2; ++s) {
        const int slice = g * 8 + wave * 2 + s;          // in batch b
        const float4* p4 = x4 + (size_t)slice * (HW / 4);
        float s0 = 0.f, s1 = 0.f, s2 = 0.f, s3 = 0.f;
#pragma unroll
        for (int i = 0; i < 4; ++i) {
            float4 a = p4[lane + (4 * i + 0) * 64];
            float4 bb = p4[lane + (4 * i + 1) * 64];
            float4 c = p4[lane + (4 * i + 2) * 64];
            float4 d = p4[lane + (4 * i + 3) * 64];
            s0 += (a.x + a.y) + (a.z + a.w);
            s1 += (bb.x + bb.y) + (bb.z + bb.w);
            s2 += (c.x + c.y) + (c.z + c.w);
            s3 += (d.x + d.y) + (d.z + d.w);
        }
        float sum = (s0 + s1) + (s2 + s3);
#pragma unroll
        for (int off = 32; off > 0; off >>= 1)
            sum += __shfl_xor(sum, off);
        if (lane == 0) atomicExch(&means[slice], sum * (1.0f / HW));
    }
    __syncthreads();   // all 4 waves' mean publishes drained (barrier waits vmcnt)

    __shared__ unsigned int sdone;
    if (tid == 0) {
        __threadfence();                         // order publishes before count
        sdone = (atomicAdd(&ctr[b], 1u) == NBLK / B - 1) ? 1u : 0u;
    }
    __syncthreads();
    const bool finisher = (sdone != 0u);         // block-uniform

    // ---------------- Phase 2: finisher computes top-3 ----------------
    __shared__ float m_lds[C];
    __shared__ unsigned long long cand[12];
    if (finisher) {
        m_lds[tid] = atomicAdd(&means[b * C + tid], 0.0f);  // coherent read
        __syncthreads();
        const float ym1 = (tid > 0)     ? m_lds[tid - 1] : 0.f;  // SAME pad
        const float y0  = m_lds[tid];
        const float yp1 = (tid < C - 1) ? m_lds[tid + 1] : 0.f;
        const float y = w[0] * ym1 + w[1] * y0 + w[2] * yp1;

        unsigned int u = __float_as_uint(y);     // monotonic float->uint
        u = (u & 0x80000000u) ? ~u : (u | 0x80000000u);
        const unsigned long long key =
            ((unsigned long long)u << 8) | (unsigned long long)(255 - tid);

        bool excluded = false;
#pragma unroll
        for (int r = 0; r < 3; ++r) {
            unsigned long long k = excluded ? 0ULL : key;
#pragma unroll
            for (int off = 32; off > 0; off >>= 1) {
                unsigned long long o = __shfl_xor(k, off);
                k = (o > k) ? o : k;
            }
            if ((tid & 63) == 0) cand[wave * 3 + r] = k;
            if (key == k) excluded = true;
        }
        __syncthreads();

        if (tid == 0) {
            unsigned long long k0 = 0, k1 = 0, k2 = 0;
#pragma unroll
            for (int i = 0; i < 12; ++i) {
                const unsigned long long v = cand[i];
                if (v > k0)      { k2 = k1; k1 = k0; k0 = v; }
                else if (v > k1) { k2 = k1; k1 = v; }
                else if (v > k2) { k2 = v; }
            }
            const unsigned int i0 = 255u - (unsigned int)(k0 & 0xFFULL);
            const unsigned int i1 = 255u - (unsigned int)(k1 & 0xFFULL);
            const unsigned int i2 = 255u - (unsigned int)(k2 & 0xFFULL);
            const unsigned int packed =
                0x80000000u | (i0 << 16) | (i1 << 8) | i2;
            atomicExch(&flag[b], packed);        // publish idx + ready bit
        }
    }

    // ---------------- Phase 3: wait for idx, copy 96 float4 ----------------
    __shared__ unsigned int spacked;
    if (tid == 0) {
        unsigned int p;
        while ((((p = atomicOr(&flag[b], 0u))) & 0x80000000u) == 0u)
            __builtin_amdgcn_s_sleep(8);
        spacked = p;
    }
    __syncthreads();
    const unsigned int packed = spacked;

    if (tid < 96) {
        const int g4 = g * 96 + tid;             // global output float4 index
        const int bj = g4 >> 10;                 // out slice = b*3 + jj
        const int jj = bj - (bj / 3) * 3;
        const int ch = (int)((packed >> (16 - 8 * jj)) & 0xFFu);
        float4* out4 = reinterpret_cast<float4*>(out);
        out4[g4] = x4[(size_t)(b * C + ch) * (HW / 4) + (g4 & (HW / 4 - 1))];
    }
}

extern "C" void kernel_launch(void* const* d_in, const int* in_sizes, int n_in,
                              void* d_out, int out_size, void* d_ws, size_t ws_size,
                              hipStream_t stream) {
    const float* x      = (const float*)d_in[0];
    const float* conv_w = (const float*)d_in[1];
    float* out = (float*)d_out;

    // Workspace: [0,32KB) means; [32KB, 32KB+128) ctr[32]; then flag[32].
    float*        means = (float*)d_ws;
    unsigned int* ctr   = (unsigned int*)((char*)d_ws + BC * sizeof(float));
    unsigned int* flag  = ctr + 32;

    // Zero control words each call (d_ws is 0xAA-poisoned, not re-poisoned).
    hipMemsetAsync((void*)ctr, 0, 64 * sizeof(unsigned int), stream);

    eca_one_kernel<<<NBLK, 256, 0, stream>>>(x, conv_w, means, ctr, flag, out);
}

// Round 10
// 29.575 us; speedup vs baseline: 2.2374x; 2.2374x over previous
//
#include <hip/hip_runtime.h>

// Problem shape (fixed by reference setup_inputs):
//   x: [B=32, C=256, H=64, W=64] fp32, conv_w: [1,1,3] fp32
//   out: [B, 3, H, W] fp32
#define B  32
#define C  256
#define HW 4096          // 64*64
#define BC (B * C)       // 8192

typedef float f32x4 __attribute__((ext_vector_type(4)));  // nt-builtin-compatible

// ---------------------------------------------------------------------------
// Kernel 1: per-(b,c) spatial mean. ONE WAVE per slice (R2 structure, proven
// 28.8us). A/B change vs R2: nontemporal loads (nt hint — x is a 134 MB
// one-shot stream, don't allocate it in L2).
// 2048 blocks x 256 threads = 8192 waves = 8192 slices.
// ---------------------------------------------------------------------------
__global__ __launch_bounds__(256) void eca_mean_kernel(
    const float* __restrict__ x, float* __restrict__ means) {
    const int wid  = (blockIdx.x * 256 + threadIdx.x) >> 6;  // slice id
    const int lane = threadIdx.x & 63;
    const f32x4* p4 = reinterpret_cast<const f32x4*>(x + (size_t)wid * HW);

    float s0 = 0.f, s1 = 0.f, s2 = 0.f, s3 = 0.f;
#pragma unroll
    for (int i = 0; i < 4; ++i) {
        f32x4 a = __builtin_nontemporal_load(&p4[lane + (4 * i + 0) * 64]);
        f32x4 b = __builtin_nontemporal_load(&p4[lane + (4 * i + 1) * 64]);
        f32x4 c = __builtin_nontemporal_load(&p4[lane + (4 * i + 2) * 64]);
        f32x4 d = __builtin_nontemporal_load(&p4[lane + (4 * i + 3) * 64]);
        s0 += (a.x + a.y) + (a.z + a.w);
        s1 += (b.x + b.y) + (b.z + b.w);
        s2 += (c.x + c.y) + (c.z + c.w);
        s3 += (d.x + d.y) + (d.z + d.w);
    }
    float sum = (s0 + s1) + (s2 + s3);
#pragma unroll
    for (int off = 32; off > 0; off >>= 1)
        sum += __shfl_xor(sum, off);

    if (lane == 0) means[wid] = sum * (1.0f / HW);
}

// ---------------------------------------------------------------------------
// Kernel 2 (byte-identical to R2, proven): fused conv1d(k=3,SAME) + top-3 +
// gather. Grid: 32 batches x 12 chunks = 384 blocks, 256 threads.
// Sigmoid monotonic -> skipped. Key = (mono_u32(y)<<8) | (255-c) reproduces
// lax.top_k's smaller-index tie-break under max-reduce.
// ---------------------------------------------------------------------------
__global__ __launch_bounds__(256) void eca_fused_kernel(
    const float* __restrict__ x, const float* __restrict__ means,
    const float* __restrict__ w, float* __restrict__ out) {
    const int b  = blockIdx.x / 12;
    const int j  = blockIdx.x % 12;
    const int jj = j >> 2;   // which of the 3 output slices
    const int q  = j & 3;    // which quarter of the slice
    const int c  = threadIdx.x;
    const int wave = c >> 6;

    const float* m = means + b * C;
    const float ym1 = (c > 0)     ? m[c - 1] : 0.f;  // SAME zero-pad
    const float y0  = m[c];
    const float yp1 = (c < C - 1) ? m[c + 1] : 0.f;
    const float y = w[0] * ym1 + w[1] * y0 + w[2] * yp1;

    // Monotonic float->uint (total order matching float compare)
    unsigned int u = __float_as_uint(y);
    u = (u & 0x80000000u) ? ~u : (u | 0x80000000u);
    const unsigned long long key =
        ((unsigned long long)u << 8) | (unsigned long long)(255 - c);

    __shared__ unsigned long long cand[12];

    bool excluded = false;
#pragma unroll
    for (int r = 0; r < 3; ++r) {
        unsigned long long k = excluded ? 0ULL : key;
#pragma unroll
        for (int off = 32; off > 0; off >>= 1) {
            unsigned long long o = __shfl_xor(k, off);
            k = (o > k) ? o : k;
        }
        if ((c & 63) == 0) cand[wave * 3 + r] = k;
        if (key == k) excluded = true;
    }
    __syncthreads();

    unsigned long long k0 = 0, k1 = 0, k2 = 0;
#pragma unroll
    for (int i = 0; i < 12; ++i) {
        const unsigned long long v = cand[i];
        if (v > k0)      { k2 = k1; k1 = k0; k0 = v; }
        else if (v > k1) { k2 = k1; k1 = v; }
        else if (v > k2) { k2 = v; }
    }
    const unsigned long long kw = (jj == 0) ? k0 : (jj == 1) ? k1 : k2;
    const int mych = 255 - (int)(kw & 0xFFULL);

    // Copy quarter q of slice (b, mych) -> out slice (b, jj).
    const float4* src = reinterpret_cast<const float4*>(
        x + ((size_t)(b * C + mych)) * HW);
    float4* dst = reinterpret_cast<float4*>(
        out + ((size_t)(b * 3 + jj)) * HW);
    const int o = q * 256 + c;   // 1024 float4 per slice, 256 per quarter
    dst[o] = src[o];
}

extern "C" void kernel_launch(void* const* d_in, const int* in_sizes, int n_in,
                              void* d_out, int out_size, void* d_ws, size_t ws_size,
                              hipStream_t stream) {
    const float* x      = (const float*)d_in[0];
    const float* conv_w = (const float*)d_in[1];
    float* out = (float*)d_out;

    float* means = (float*)d_ws;   // 8192 f32 = 32 KB

    eca_mean_kernel<<<BC / 4, 256, 0, stream>>>(x, means);
    eca_fused_kernel<<<B * 12, 256, 0, stream>>>(x, means, conv_w, out);
}